// Round 3
// baseline (291.915 us; speedup 1.0000x reference)
//
#include <hip/hip_runtime.h>
#include <cstdint>
#include <cstddef>

// GraphSAGE 3-layer, N=100000 nodes, E=1600000 edges, dims 64->64->64->32.
// Transform-then-aggregate; padded CSR via 256-node super-buckets;
// weights pre-swizzled once into MFMA B-frag layout (init_ws kernel);
// per-layer dual GEMMs (t=h@Wl, r=h@Wr+b, mfma_f32_16x16x32_bf16) LDS-free,
// barrier-free; t for layers 0/1 fp8 e4m3, t2 bf16; r bf16 L0/L1, fp32 L2.
// R15: t-tables SPLIT into two 3.2MB feature-halves ([N][32B] each) so the
//      gather's random-read working set fits the 4MiB per-XCD L2 (read-only
//      replication); gathers run 2 temporal passes (hf = blockIdx>=G, one
//      dispatch, 4 lanes/node, 8B loads); colidx/r loads + X/out stores are
//      nontemporal to protect table residency. colidx read 2x per gather
//      (+3.4us HBM) traded against L2-hit random reads.
// R14: csr+gemm0 merged; init_ws; pad-4 CSR. -12us (boundary ~3.5us each).
// R13: pad-8 sentinel CSR; r bf16 L0/L1. -12us; gathers are BW-bound, NOT
//      divergence-bound (tail removal was neutral).
// R4: LDS-atomic aggregation is 12x slower than CSR gather — don't revisit.
// R6: per-node scatter -> 64B-line write amplification, keep super-buckets.
// R10: gather+GEMM fusion halves occupancy, couples imbalance — keep split.
// R12: R11's "slow GEMM" was broken weight staging; fp8 gather is the win.

constexpr int SBW = 256;     // dst nodes per super-bucket
constexpr int LOGSBW = 8;
constexpr int CAPS = 4608;   // super capacity (unpadded); mean 4096, +8 sigma
constexpr int CAPSP = 5632;  // padded capacity; mean ~4608 (pad-4), %16==0
constexpr int CHK = 2048;    // edges per bin block -> 782 blocks

typedef __attribute__((ext_vector_type(8))) short s16x8;
typedef __attribute__((ext_vector_type(4))) float f32x4;
typedef __attribute__((ext_vector_type(2))) float f32x2;
typedef __attribute__((ext_vector_type(4))) int i32x4;

__device__ inline unsigned short f2bf(float f) {
  unsigned u = __builtin_bit_cast(unsigned, f);
  u += 0x7FFFu + ((u >> 16) & 1u);          // round-to-nearest-even
  return (unsigned short)(u >> 16);
}
__device__ inline float bf2f(unsigned short b) {
  unsigned u = ((unsigned)b) << 16;
  return __builtin_bit_cast(float, u);
}
__device__ inline unsigned char f2fp8(float f) {
  int p = __builtin_amdgcn_cvt_pk_fp8_f32(f, f, 0, false);
  return (unsigned char)(p & 0xFF);
}

// ------- init: zero bcur (block 0) + weight swizzle (blocks 1..40) ---------
// Swizzle: per layer 2*NTT tiles (Wl then Wr); per tile 2 planes (k<32,
// k>=32); per plane 64 lanes x 8 bf16: W[k=plane*32+q*8+j][col=c*16+m].
// Layer short offsets: L0=0, L1=8192, L2=16384. gemm fetch:
// frag = Wsw[off + (c*2+plane)*512 + lane*8 ..+8] (16B/lane, coalesced).

__global__ __launch_bounds__(256) void init_ws(int* __restrict__ bcur, int NSB,
                                               const float* __restrict__ Wl0,
                                               const float* __restrict__ Wr0,
                                               const float* __restrict__ Wl1,
                                               const float* __restrict__ Wr1,
                                               const float* __restrict__ Wl2,
                                               const float* __restrict__ Wr2,
                                               unsigned short* __restrict__ Wsw) {
  const int tid = threadIdx.x;
  if (blockIdx.x == 0) {
    for (int i = tid; i < NSB; i += 256) bcur[i] = 0;
    return;
  }
  int g = (blockIdx.x - 1) * 256 + tid;        // u32 index
  if (g >= 10240) return;
  int s = g * 2;                               // short index (j even)
  int layer, off;
  if (s < 8192)       { layer = 0; off = 0; }
  else if (s < 16384) { layer = 1; off = 8192; }
  else                { layer = 2; off = 16384; }
  int t = s - off;
  int D = (layer == 2) ? 32 : 64;
  int NTT = D / 16;
  int tt = t >> 10;
  int rem = t & 1023;
  int plane = rem >> 9;
  int rem2 = rem & 511;
  int lane = rem2 >> 3;
  int j = rem2 & 7;
  int q = lane >> 4, m = lane & 15;
  int k = plane * 32 + q * 8 + j;
  const float* W;
  int c;
  if (tt < NTT) {
    c = tt;
    W = (layer == 0) ? Wl0 : (layer == 1) ? Wl1 : Wl2;
  } else {
    c = tt - NTT;
    W = (layer == 0) ? Wr0 : (layer == 1) ? Wr1 : Wr2;
  }
  int col = c * 16 + m;
  unsigned lo = f2bf(W[k * D + col]);
  unsigned hi = f2bf(W[(k + 1) * D + col]);
  *(unsigned*)&Wsw[s] = lo | (hi << 16);
}

// ------- pass 1: coarse bin into 256-node super-buckets --------------------

__global__ __launch_bounds__(256) void bin_coarse(const int* __restrict__ src,
                                                  const int* __restrict__ dst,
                                                  int* __restrict__ bcur,
                                                  unsigned int* __restrict__ coarse,
                                                  int NSB, int E) {
  __shared__ int h[512];
  __shared__ unsigned ed[CHK];
  __shared__ short sb[CHK];
  const int tid = threadIdx.x;
  for (int i = tid; i < NSB; i += 256) h[i] = 0;
  __syncthreads();
  const int e0 = blockIdx.x * CHK;
  const int e1 = min(E, e0 + CHK);
  for (int e = e0 + tid; e < e1; e += 256) {
    int d = dst[e];
    int s = src[e];
    int b = d >> LOGSBW;
    ed[e - e0] = (unsigned)s | ((unsigned)(d & (SBW - 1)) << 17);
    sb[e - e0] = (short)b;
    atomicAdd(&h[b], 1);
  }
  __syncthreads();
  for (int i = tid; i < NSB; i += 256) {
    int c = h[i];
    h[i] = c ? (i * CAPS + atomicAdd(&bcur[i], c)) : 0;  // slot -> abs cursor
  }
  __syncthreads();
  const int n = e1 - e0;
  for (int k = tid; k < n; k += 256) {
    int b = sb[k];
    int pos = atomicAdd(&h[b], 1);
    if (pos < (b + 1) * CAPS)                 // overflow guard (never taken)
      coarse[pos] = ed[k];
  }
}

// ------- pass 2: per-super count/scan/sort -> PADDED CSR, merged with -----
// ------- layer-0 dual GEMM (independent work, fills the idle CUs) ---------
// CSR: blocks [0,NSB). Segments padded to x4 with sentinel colidx=N (row N
// of t half-tables is zero). GEMM0: blocks [NSB, NSB+gb): fp32 x ->
// t0 fp8 (split halves) + r0 bf16.
// C/D layout: col=lane&15, row=(lane>>4)*4+reg (m89-verified).

__global__ __launch_bounds__(256) void csr_gemm0(const unsigned int* __restrict__ coarse,
                                                 const int* __restrict__ bcur,
                                                 int* __restrict__ rowstart,
                                                 int* __restrict__ degarr,
                                                 float* __restrict__ deg_inv,
                                                 int* __restrict__ colidx,
                                                 const float* __restrict__ x,
                                                 const unsigned short* __restrict__ Wf,
                                                 const float* __restrict__ bias,
                                                 unsigned char* __restrict__ t_lo,
                                                 unsigned char* __restrict__ t_hi,
                                                 unsigned short* __restrict__ r_out,
                                                 int N, int NSB) {
  __shared__ int cnt[SBW];
  __shared__ int sc[SBW];
  __shared__ int cur[SBW];
  const int tid = threadIdx.x;
  if ((int)blockIdx.x < NSB) {
    // ---------------- CSR path ----------------
    const int b = blockIdx.x;
    cnt[tid] = 0;
    __syncthreads();
    const int ec = min(bcur[b], CAPS);
    const int baseC = b * CAPS;
    const int baseP = b * CAPSP;
    for (int e = tid; e < ec; e += 256)
      atomicAdd(&cnt[coarse[baseC + e] >> 17], 1);
    __syncthreads();
    int v = cnt[tid];
    int pc = (v + 3) & ~3;                      // padded count (x4)
    sc[tid] = pc;
    __syncthreads();
    for (int off = 1; off < SBW; off <<= 1) {
      int y = sc[tid];
      if (tid >= off) y += sc[tid - off];
      __syncthreads();
      sc[tid] = y;
      __syncthreads();
    }
    int pex = sc[tid] - pc;                     // exclusive padded prefix
    cur[tid] = pex;
    int gn = b * SBW + tid;
    if (gn < N) {
      rowstart[gn] = baseP + pex;
      degarr[gn] = pc;                          // padded extent for the gather
      deg_inv[gn] = 1.0f / (float)(v > 1 ? v : 1);
    }
    __syncthreads();
    for (int e = tid; e < ec; e += 256) {
      unsigned p = coarse[baseC + e];
      int dl = (int)(p >> 17);
      int s = (int)(p & 0x1FFFFu);
      int l = atomicAdd(&cur[dl], 1);
      if (l < CAPSP)                            // overflow guard (never taken)
        colidx[baseP + l] = s;
    }
    // sentinel padding (disjoint from scatter range, no sync needed)
    int pe = pex + pc;
    if (pe > CAPSP) pe = CAPSP;
    for (int l = pex + v; l < pe; ++l) colidx[baseP + l] = N;
    return;
  }
  // ---------------- GEMM0 path ----------------
  constexpr int NTT = 4;
  const int gbid = blockIdx.x - NSB;
  if (gbid == 0 && tid < 16) {                 // zero sentinel row N (32B/half)
    unsigned char* th = (tid < 8) ? t_lo : t_hi;
    ((unsigned*)th)[(size_t)N * 8 + (tid & 7)] = 0u;
  }
  const int wv = tid >> 6, lane = tid & 63;
  const int q = lane >> 4, m = lane & 15;
  const int row = gbid * 64 + wv * 16 + m;
  const int rowc = row < N ? row : N - 1;
  const float* xp = &x[(size_t)rowc * 64];
  float4 f0 = *(const float4*)&xp[q * 8];
  float4 f1 = *(const float4*)&xp[q * 8 + 4];
  float4 f2 = *(const float4*)&xp[32 + q * 8];
  float4 f3 = *(const float4*)&xp[32 + q * 8 + 4];
  s16x8 a0, a1;
  a0[0] = (short)f2bf(f0.x); a0[1] = (short)f2bf(f0.y);
  a0[2] = (short)f2bf(f0.z); a0[3] = (short)f2bf(f0.w);
  a0[4] = (short)f2bf(f1.x); a0[5] = (short)f2bf(f1.y);
  a0[6] = (short)f2bf(f1.z); a0[7] = (short)f2bf(f1.w);
  a1[0] = (short)f2bf(f2.x); a1[1] = (short)f2bf(f2.y);
  a1[2] = (short)f2bf(f2.z); a1[3] = (short)f2bf(f2.w);
  a1[4] = (short)f2bf(f3.x); a1[5] = (short)f2bf(f3.y);
  a1[6] = (short)f2bf(f3.z); a1[7] = (short)f2bf(f3.w);

  f32x4 acc[2 * NTT];
#pragma unroll
  for (int c = 0; c < 2 * NTT; ++c) acc[c] = (f32x4){0.f, 0.f, 0.f, 0.f};
#pragma unroll
  for (int c = 0; c < 2 * NTT; ++c) {
    s16x8 b0 = *(const s16x8*)&Wf[(c * 2 + 0) * 512 + lane * 8];
    s16x8 b1 = *(const s16x8*)&Wf[(c * 2 + 1) * 512 + lane * 8];
    acc[c] = __builtin_amdgcn_mfma_f32_16x16x32_bf16(a0, b0, acc[c], 0, 0, 0);
    acc[c] = __builtin_amdgcn_mfma_f32_16x16x32_bf16(a1, b1, acc[c], 0, 0, 0);
  }

  const int orow = gbid * 64 + wv * 16 + q * 4;
#pragma unroll
  for (int c = 0; c < NTT; ++c) {
    unsigned char* th = (c < 2) ? t_lo : t_hi;
    const int f = (c & 1) * 16 + m;            // feature within half
#pragma unroll
    for (int i = 0; i < 4; ++i) {
      int r_ = orow + i;
      if (r_ < N) th[(size_t)r_ * 32 + f] = f2fp8(acc[c][i]);
    }
  }
#pragma unroll
  for (int c = 0; c < NTT; ++c) {
    float bv = bias[c * 16 + m];
#pragma unroll
    for (int i = 0; i < 4; ++i) {
      int r_ = orow + i;
      if (r_ < N) r_out[(size_t)r_ * 64 + c * 16 + m] = f2bf(acc[NTT + c][i] + bv);
    }
  }
}

// ------- mid/final MFMA dual GEMM, bf16 input, LDS-free --------------------
// TFP8: t out fp8 halves (layer 1) else bf16 halves (layer 2).
// RB16: r out bf16 else fp32. Half rows are 32B in both t dtypes.

template <int DOUT, bool TFP8, bool RB16>
__global__ __launch_bounds__(256) void gemm_mfma(const unsigned short* __restrict__ Hm,
                                                 const unsigned short* __restrict__ Wf,
                                                 const float* __restrict__ bias,
                                                 void* __restrict__ t_lo,
                                                 void* __restrict__ t_hi,
                                                 void* __restrict__ r_out, int N) {
  constexpr int NTT = DOUT / 16;
  const int tid = threadIdx.x;
  if (blockIdx.x == 0 && tid < 16) {           // zero sentinel row N (32B/half)
    void* th = (tid < 8) ? t_lo : t_hi;
    ((unsigned*)th)[(size_t)N * 8 + (tid & 7)] = 0u;
  }
  const int wv = tid >> 6, lane = tid & 63;
  const int q = lane >> 4, m = lane & 15;
  const int row = blockIdx.x * 64 + wv * 16 + m;
  const int rowc = row < N ? row : N - 1;
  const s16x8 a0 = *(const s16x8*)&Hm[(size_t)rowc * 64 + q * 8];
  const s16x8 a1 = *(const s16x8*)&Hm[(size_t)rowc * 64 + 32 + q * 8];

  f32x4 acc[2 * NTT];
#pragma unroll
  for (int c = 0; c < 2 * NTT; ++c) acc[c] = (f32x4){0.f, 0.f, 0.f, 0.f};
#pragma unroll
  for (int c = 0; c < 2 * NTT; ++c) {
    s16x8 b0 = *(const s16x8*)&Wf[(c * 2 + 0) * 512 + lane * 8];
    s16x8 b1 = *(const s16x8*)&Wf[(c * 2 + 1) * 512 + lane * 8];
    acc[c] = __builtin_amdgcn_mfma_f32_16x16x32_bf16(a0, b0, acc[c], 0, 0, 0);
    acc[c] = __builtin_amdgcn_mfma_f32_16x16x32_bf16(a1, b1, acc[c], 0, 0, 0);
  }

  const int orow = blockIdx.x * 64 + wv * 16 + q * 4;
#pragma unroll
  for (int c = 0; c < NTT; ++c) {
    void* th;
    int f;
    if (TFP8) { th = (c < 2) ? t_lo : t_hi; f = (c & 1) * 16 + m; }
    else      { th = (c == 0) ? t_lo : t_hi; f = m; }
#pragma unroll
    for (int i = 0; i < 4; ++i) {
      int r_ = orow + i;
      if (r_ < N) {
        if (TFP8)
          ((unsigned char*)th)[(size_t)r_ * 32 + f] = f2fp8(acc[c][i]);
        else
          ((unsigned short*)th)[(size_t)r_ * 16 + f] = f2bf(acc[c][i]);
      }
    }
  }
#pragma unroll
  for (int c = 0; c < NTT; ++c) {
    float bv = bias[c * 16 + m];
#pragma unroll
    for (int i = 0; i < 4; ++i) {
      int r_ = orow + i;
      if (r_ < N) {
        if (RB16)
          ((unsigned short*)r_out)[(size_t)r_ * DOUT + c * 16 + m] =
              f2bf(acc[NTT + c][i] + bv);
        else
          ((float*)r_out)[(size_t)r_ * DOUT + c * 16 + m] = acc[NTT + c][i] + bv;
      }
    }
  }
}

// ------- gather (fp8 t halves): h = bf16(elu(deg_inv*sum t[src] + r)) ------
// Two temporal passes over the grid (hf = blockIdx>=G) so the active half-
// table (3.2MB) is L2-resident per XCD. 4 lanes/node, uint2 = 8 fp8 feats
// per lane; colidx/r nontemporal loads, X nontemporal store.

__global__ __launch_bounds__(256) void gather_fp8(const uint2* __restrict__ tlo,
                                                  const uint2* __restrict__ thi,
                                                  const unsigned short* __restrict__ r,
                                                  const float* __restrict__ deg_inv,
                                                  const int* __restrict__ rowstart,
                                                  const int* __restrict__ degarr,
                                                  const int* __restrict__ colidx,
                                                  unsigned short* __restrict__ Xout,
                                                  int N, int G) {
  const int hf = (int)blockIdx.x >= G;
  const int blk = hf ? (int)blockIdx.x - G : (int)blockIdx.x;
  const int node = blk * 64 + ((int)threadIdx.x >> 2);
  const int lane = threadIdx.x & 3;
  if (node >= N) return;
  const uint2* t = hf ? thi : tlo;
  int b = rowstart[node];
  int e = b + degarr[node];                    // padded, multiple of 4
  float s[8];
#pragma unroll
  for (int k = 0; k < 8; ++k) s[k] = 0.f;
  int i = b;
  for (; i + 8 <= e; i += 8) {
    i32x4 c0 = __builtin_nontemporal_load((const i32x4*)&colidx[i]);
    i32x4 c1 = __builtin_nontemporal_load((const i32x4*)&colidx[i + 4]);
    uint2 v[8];
    v[0] = t[(size_t)c0.x * 4 + lane];
    v[1] = t[(size_t)c0.y * 4 + lane];
    v[2] = t[(size_t)c0.z * 4 + lane];
    v[3] = t[(size_t)c0.w * 4 + lane];
    v[4] = t[(size_t)c1.x * 4 + lane];
    v[5] = t[(size_t)c1.y * 4 + lane];
    v[6] = t[(size_t)c1.z * 4 + lane];
    v[7] = t[(size_t)c1.w * 4 + lane];
#pragma unroll
    for (int j = 0; j < 8; ++j) {
      f32x2 p0 = __builtin_amdgcn_cvt_pk_f32_fp8((int)v[j].x, false);
      f32x2 p1 = __builtin_amdgcn_cvt_pk_f32_fp8((int)v[j].x, true);
      f32x2 p2 = __builtin_amdgcn_cvt_pk_f32_fp8((int)v[j].y, false);
      f32x2 p3 = __builtin_amdgcn_cvt_pk_f32_fp8((int)v[j].y, true);
      s[0] += p0[0]; s[1] += p0[1]; s[2] += p1[0]; s[3] += p1[1];
      s[4] += p2[0]; s[5] += p2[1]; s[6] += p3[0]; s[7] += p3[1];
    }
  }
  if (i < e) {                                 // exactly 4 remain
    i32x4 c0 = __builtin_nontemporal_load((const i32x4*)&colidx[i]);
    uint2 v[4];
    v[0] = t[(size_t)c0.x * 4 + lane];
    v[1] = t[(size_t)c0.y * 4 + lane];
    v[2] = t[(size_t)c0.z * 4 + lane];
    v[3] = t[(size_t)c0.w * 4 + lane];
#pragma unroll
    for (int j = 0; j < 4; ++j) {
      f32x2 p0 = __builtin_amdgcn_cvt_pk_f32_fp8((int)v[j].x, false);
      f32x2 p1 = __builtin_amdgcn_cvt_pk_f32_fp8((int)v[j].x, true);
      f32x2 p2 = __builtin_amdgcn_cvt_pk_f32_fp8((int)v[j].y, false);
      f32x2 p3 = __builtin_amdgcn_cvt_pk_f32_fp8((int)v[j].y, true);
      s[0] += p0[0]; s[1] += p0[1]; s[2] += p1[0]; s[3] += p1[1];
      s[4] += p2[0]; s[5] += p2[1]; s[6] += p3[0]; s[7] += p3[1];
    }
  }
  float dv = deg_inv[node];
  const s16x8 rv = __builtin_nontemporal_load(
      (const s16x8*)&r[(size_t)node * 64 + hf * 32 + lane * 8]);
  s16x8 hv;
#pragma unroll
  for (int k = 0; k < 8; ++k) {
    float ak = s[k] * dv + bf2f((unsigned short)rv[k]);
    ak = ak > 0.f ? ak : (expf(ak) - 1.f);
    hv[k] = (short)f2bf(ak);
  }
  __builtin_nontemporal_store(hv,
      (s16x8*)&Xout[(size_t)node * 64 + hf * 32 + lane * 8]);
}

// ------- final gather: out = deg_inv * sum t2[src] + r[dst], t2 bf16 -------
// Same 2-pass half-table scheme; 4 lanes/node, uint2 = 4 bf16 per lane.

__global__ __launch_bounds__(256) void gather_out(const uint2* __restrict__ tlo,
                                                  const uint2* __restrict__ thi,
                                                  const float* __restrict__ r,
                                                  const float* __restrict__ deg_inv,
                                                  const int* __restrict__ rowstart,
                                                  const int* __restrict__ degarr,
                                                  const int* __restrict__ colidx,
                                                  float* __restrict__ out,
                                                  int N, int G) {
  const int hf = (int)blockIdx.x >= G;
  const int blk = hf ? (int)blockIdx.x - G : (int)blockIdx.x;
  const int node = blk * 64 + ((int)threadIdx.x >> 2);
  const int lane = threadIdx.x & 3;
  if (node >= N) return;
  const uint2* t = hf ? thi : tlo;
  int b = rowstart[node];
  int e = b + degarr[node];            // padded, multiple of 4
  float s0 = 0.f, s1 = 0.f, s2 = 0.f, s3 = 0.f;
  int i = b;
  for (; i + 8 <= e; i += 8) {
    i32x4 c0 = __builtin_nontemporal_load((const i32x4*)&colidx[i]);
    i32x4 c1 = __builtin_nontemporal_load((const i32x4*)&colidx[i + 4]);
    uint2 v[8];
    v[0] = t[(size_t)c0.x * 4 + lane];
    v[1] = t[(size_t)c0.y * 4 + lane];
    v[2] = t[(size_t)c0.z * 4 + lane];
    v[3] = t[(size_t)c0.w * 4 + lane];
    v[4] = t[(size_t)c1.x * 4 + lane];
    v[5] = t[(size_t)c1.y * 4 + lane];
    v[6] = t[(size_t)c1.z * 4 + lane];
    v[7] = t[(size_t)c1.w * 4 + lane];
#pragma unroll
    for (int j = 0; j < 8; ++j) {
      s0 += bf2f((unsigned short)(v[j].x & 0xFFFFu));
      s1 += bf2f((unsigned short)(v[j].x >> 16));
      s2 += bf2f((unsigned short)(v[j].y & 0xFFFFu));
      s3 += bf2f((unsigned short)(v[j].y >> 16));
    }
  }
  if (i < e) {                          // exactly 4 remain
    i32x4 c0 = __builtin_nontemporal_load((const i32x4*)&colidx[i]);
    uint2 v[4];
    v[0] = t[(size_t)c0.x * 4 + lane];
    v[1] = t[(size_t)c0.y * 4 + lane];
    v[2] = t[(size_t)c0.z * 4 + lane];
    v[3] = t[(size_t)c0.w * 4 + lane];
#pragma unroll
    for (int j = 0; j < 4; ++j) {
      s0 += bf2f((unsigned short)(v[j].x & 0xFFFFu));
      s1 += bf2f((unsigned short)(v[j].x >> 16));
      s2 += bf2f((unsigned short)(v[j].y & 0xFFFFu));
      s3 += bf2f((unsigned short)(v[j].y >> 16));
    }
  }
  float dv = deg_inv[node];
  f32x4 rv = __builtin_nontemporal_load(
      (const f32x4*)&r[(size_t)node * 32 + hf * 16 + lane * 4]);
  f32x4 o;
  o[0] = s0 * dv + rv[0]; o[1] = s1 * dv + rv[1];
  o[2] = s2 * dv + rv[2]; o[3] = s3 * dv + rv[3];
  __builtin_nontemporal_store(o,
      (f32x4*)&out[(size_t)node * 32 + hf * 16 + lane * 4]);
}

// ---------------- launch ----------------

extern "C" void kernel_launch(void* const* d_in, const int* in_sizes, int n_in,
                              void* d_out, int out_size, void* d_ws, size_t ws_size,
                              hipStream_t stream) {
  const float* x   = (const float*)d_in[0];
  const int*   ei  = (const int*)d_in[1];
  const float* Wl0 = (const float*)d_in[2];
  const float* Wr0 = (const float*)d_in[3];
  const float* b0  = (const float*)d_in[4];
  const float* Wl1 = (const float*)d_in[5];
  const float* Wr1 = (const float*)d_in[6];
  const float* b1  = (const float*)d_in[7];
  const float* Wl2 = (const float*)d_in[8];
  const float* Wr2 = (const float*)d_in[9];
  const float* b2  = (const float*)d_in[10];
  float* out = (float*)d_out;

  const int N = in_sizes[0] / 64;   // 100000
  const int E = in_sizes[1] / 2;    // 1600000
  const int* srcv = ei;
  const int* dstv = ei + E;
  const int NSB = (N + SBW - 1) >> LOGSBW;   // 391

  auto al = [](size_t v) { return (v + 255) & ~(size_t)255; };
  char* w = (char*)d_ws;
  size_t halfT = al((size_t)(N + 1) * 32);   // one 32B-row half-table
  size_t oBcur = 0;
  size_t oRow  = oBcur + al(4 * (size_t)NSB);
  size_t oDeg  = oRow + al(4 * (size_t)N);
  size_t oDinv = oDeg + al(4 * (size_t)N);
  size_t oWsw  = oDinv + al(4 * (size_t)N);
  size_t oBin  = oWsw + al(2 * 20480);
  size_t oCol  = oBin + al(4 * (size_t)NSB * CAPS);
  size_t oP8   = oCol + al(4 * (size_t)NSB * CAPSP);   // fp8 t halves (2x)
  size_t oP16  = oP8 + 2 * halfT;                      // bf16 t2 halves (2x)
  size_t oX    = oP16 + 2 * halfT;
  size_t oR    = oX + al(2 * (size_t)N * 64);          // bf16 h buffer
  // total = oR + 2*N*64  (~55 MiB); r buffer: bf16 [N][64] or fp32 [N][32]

  int*            bcur     = (int*)(w + oBcur);
  int*            rowstart = (int*)(w + oRow);
  int*            degarr   = (int*)(w + oDeg);
  float*          deg_inv  = (float*)(w + oDinv);
  unsigned short* Wsw      = (unsigned short*)(w + oWsw); // swizzled weights
  unsigned*       coarse   = (unsigned*)(w + oBin);
  int*            colidx   = (int*)(w + oCol);
  unsigned char*  P8lo     = (unsigned char*)(w + oP8);
  unsigned char*  P8hi     = P8lo + halfT;
  unsigned short* P16lo    = (unsigned short*)(w + oP16);
  unsigned short* P16hi    = (unsigned short*)(w + oP16 + halfT);
  unsigned short* X        = (unsigned short*)(w + oX);   // bf16 h
  unsigned short* Rb       = (unsigned short*)(w + oR);   // bf16 r (L0/L1)
  float*          Rf       = (float*)(w + oR);            // fp32 r (L2)

  int bbl = (E + CHK - 1) / CHK;   // 782
  int gb = (N + 63) / 64;          // 1563
  int G  = (N + 63) / 64;          // gather blocks per half-pass (64 nodes/blk)

  init_ws<<<41, 256, 0, stream>>>(bcur, NSB, Wl0, Wr0, Wl1, Wr1, Wl2, Wr2, Wsw);
  bin_coarse<<<bbl, 256, 0, stream>>>(srcv, dstv, bcur, coarse, NSB, E);
  // CSR build (blocks [0,NSB)) overlapped with layer-0 GEMM (blocks [NSB,..))
  csr_gemm0<<<NSB + gb, 256, 0, stream>>>(coarse, bcur, rowstart, degarr,
                                          deg_inv, colidx, x, Wsw, b0,
                                          P8lo, P8hi, Rb, N, NSB);
  gather_fp8<<<2 * G, 256, 0, stream>>>((const uint2*)P8lo, (const uint2*)P8hi,
                                        Rb, deg_inv, rowstart, degarr, colidx,
                                        X, N, G);
  // layer 1: X -> t1 (fp8 halves), r1 (bf16 Rb)
  gemm_mfma<64, true, true><<<gb, 256, 0, stream>>>(X, Wsw + 8192, b1,
                                                    P8lo, P8hi, Rb, N);
  gather_fp8<<<2 * G, 256, 0, stream>>>((const uint2*)P8lo, (const uint2*)P8hi,
                                        Rb, deg_inv, rowstart, degarr, colidx,
                                        X, N, G);
  // layer 2: X -> t2 (bf16 halves), r2 (fp32 Rf, [N][32])
  gemm_mfma<32, false, false><<<gb, 256, 0, stream>>>(X, Wsw + 16384, b2,
                                                      P16lo, P16hi, Rf, N);
  gather_out<<<2 * G, 256, 0, stream>>>((const uint2*)P16lo, (const uint2*)P16hi,
                                        Rf, deg_inv, rowstart, degarr, colidx,
                                        out, N, G);
}

// Round 4
// 255.136 us; speedup vs baseline: 1.1442x; 1.1442x over previous
//
#include <hip/hip_runtime.h>
#include <cstdint>
#include <cstddef>

// GraphSAGE 3-layer, N=100000 nodes, E=1600000 edges, dims 64->64->64->32.
// Transform-then-aggregate; padded CSR via 256-node super-buckets;
// weights pre-swizzled once into MFMA B-frag layout (init_ws kernel);
// per-layer dual GEMMs (t=h@Wl, r=h@Wr+b, mfma_f32_16x16x32_bf16) LDS-free,
// barrier-free; t for layers 0/1 fp8 e4m3 (row=64B=1 line), t2 bf16;
// r bf16 L0/L1, fp32 L2.
// R16: REVERT R15 split-tables (regressed +49us; gather counters showed
//      latency-bound: 22% BW, 22% VALU, 54% occ — traffic was never the
//      limit). Latency attack instead: 4 lanes/node x 16B uint4 loads
//      (half the vmem instrs), software-pipelined colidx prefetch (breaks
//      colidx->t serial miss chain), per-node meta packed into one int2
//      (rowstart, degpad|deg_real<<16; deg_inv computed in-register).
// R15: half-tables + 2-pass gather REGRESSED — gathers are latency-bound;
//      L2-residency of a 3.2MB table does not survive stream eviction.
// R14: csr+gemm0 merged; init_ws; pad-4 CSR. -12us (boundary ~3.5us each).
// R13: pad-8 sentinel CSR; r bf16 L0/L1. gathers NOT divergence-bound.
// R4: LDS-atomic aggregation is 12x slower than CSR gather — don't revisit.
// R6: per-node scatter -> 64B-line write amplification, keep super-buckets.
// R10: gather+GEMM fusion halves occupancy, couples imbalance — keep split.
// R12: R11's "slow GEMM" was broken weight staging; fp8 gather is the win.

constexpr int SBW = 256;     // dst nodes per super-bucket
constexpr int LOGSBW = 8;
constexpr int CAPS = 4608;   // super capacity (unpadded); mean 4096, +8 sigma
constexpr int CAPSP = 5632;  // padded capacity; mean ~4608 (pad-4), %16==0
constexpr int CHK = 2048;    // edges per bin block -> 782 blocks

typedef __attribute__((ext_vector_type(8))) short s16x8;
typedef __attribute__((ext_vector_type(4))) float f32x4;
typedef __attribute__((ext_vector_type(2))) float f32x2;
typedef __attribute__((ext_vector_type(4))) int i32x4;
typedef __attribute__((ext_vector_type(4))) unsigned u32x4;

__device__ inline unsigned short f2bf(float f) {
  unsigned u = __builtin_bit_cast(unsigned, f);
  u += 0x7FFFu + ((u >> 16) & 1u);          // round-to-nearest-even
  return (unsigned short)(u >> 16);
}
__device__ inline float bf2f(unsigned short b) {
  unsigned u = ((unsigned)b) << 16;
  return __builtin_bit_cast(float, u);
}
__device__ inline unsigned char f2fp8(float f) {
  int p = __builtin_amdgcn_cvt_pk_fp8_f32(f, f, 0, false);
  return (unsigned char)(p & 0xFF);
}

// ------- init: zero bcur (block 0) + weight swizzle (blocks 1..40) ---------
// Swizzle: per layer 2*NTT tiles (Wl then Wr); per tile 2 planes (k<32,
// k>=32); per plane 64 lanes x 8 bf16: W[k=plane*32+q*8+j][col=c*16+m].
// Layer short offsets: L0=0, L1=8192, L2=16384. gemm fetch:
// frag = Wsw[off + (c*2+plane)*512 + lane*8 ..+8] (16B/lane, coalesced).

__global__ __launch_bounds__(256) void init_ws(int* __restrict__ bcur, int NSB,
                                               const float* __restrict__ Wl0,
                                               const float* __restrict__ Wr0,
                                               const float* __restrict__ Wl1,
                                               const float* __restrict__ Wr1,
                                               const float* __restrict__ Wl2,
                                               const float* __restrict__ Wr2,
                                               unsigned short* __restrict__ Wsw) {
  const int tid = threadIdx.x;
  if (blockIdx.x == 0) {
    for (int i = tid; i < NSB; i += 256) bcur[i] = 0;
    return;
  }
  int g = (blockIdx.x - 1) * 256 + tid;        // u32 index
  if (g >= 10240) return;
  int s = g * 2;                               // short index (j even)
  int layer, off;
  if (s < 8192)       { layer = 0; off = 0; }
  else if (s < 16384) { layer = 1; off = 8192; }
  else                { layer = 2; off = 16384; }
  int t = s - off;
  int D = (layer == 2) ? 32 : 64;
  int NTT = D / 16;
  int tt = t >> 10;
  int rem = t & 1023;
  int plane = rem >> 9;
  int rem2 = rem & 511;
  int lane = rem2 >> 3;
  int j = rem2 & 7;
  int q = lane >> 4, m = lane & 15;
  int k = plane * 32 + q * 8 + j;
  const float* W;
  int c;
  if (tt < NTT) {
    c = tt;
    W = (layer == 0) ? Wl0 : (layer == 1) ? Wl1 : Wl2;
  } else {
    c = tt - NTT;
    W = (layer == 0) ? Wr0 : (layer == 1) ? Wr1 : Wr2;
  }
  int col = c * 16 + m;
  unsigned lo = f2bf(W[k * D + col]);
  unsigned hi = f2bf(W[(k + 1) * D + col]);
  *(unsigned*)&Wsw[s] = lo | (hi << 16);
}

// ------- pass 1: coarse bin into 256-node super-buckets --------------------

__global__ __launch_bounds__(256) void bin_coarse(const int* __restrict__ src,
                                                  const int* __restrict__ dst,
                                                  int* __restrict__ bcur,
                                                  unsigned int* __restrict__ coarse,
                                                  int NSB, int E) {
  __shared__ int h[512];
  __shared__ unsigned ed[CHK];
  __shared__ short sb[CHK];
  const int tid = threadIdx.x;
  for (int i = tid; i < NSB; i += 256) h[i] = 0;
  __syncthreads();
  const int e0 = blockIdx.x * CHK;
  const int e1 = min(E, e0 + CHK);
  for (int e = e0 + tid; e < e1; e += 256) {
    int d = dst[e];
    int s = src[e];
    int b = d >> LOGSBW;
    ed[e - e0] = (unsigned)s | ((unsigned)(d & (SBW - 1)) << 17);
    sb[e - e0] = (short)b;
    atomicAdd(&h[b], 1);
  }
  __syncthreads();
  for (int i = tid; i < NSB; i += 256) {
    int c = h[i];
    h[i] = c ? (i * CAPS + atomicAdd(&bcur[i], c)) : 0;  // slot -> abs cursor
  }
  __syncthreads();
  const int n = e1 - e0;
  for (int k = tid; k < n; k += 256) {
    int b = sb[k];
    int pos = atomicAdd(&h[b], 1);
    if (pos < (b + 1) * CAPS)                 // overflow guard (never taken)
      coarse[pos] = ed[k];
  }
}

// ------- pass 2: per-super count/scan/sort -> PADDED CSR, merged with -----
// ------- layer-0 dual GEMM (independent work, fills the idle CUs) ---------
// CSR: blocks [0,NSB). Segments padded to x4 with sentinel colidx=N (row N
// of t tables is zero). Per-node meta int2 = (rowstart, degpad|deg_real<<16).
// GEMM0: blocks [NSB, NSB+gb): fp32 x -> t0 fp8 + r0 bf16.
// C/D layout: col=lane&15, row=(lane>>4)*4+reg (m89-verified).

__global__ __launch_bounds__(256) void csr_gemm0(const unsigned int* __restrict__ coarse,
                                                 const int* __restrict__ bcur,
                                                 int2* __restrict__ meta,
                                                 int* __restrict__ colidx,
                                                 const float* __restrict__ x,
                                                 const unsigned short* __restrict__ Wf,
                                                 const float* __restrict__ bias,
                                                 unsigned char* __restrict__ t_out,
                                                 unsigned short* __restrict__ r_out,
                                                 int N, int NSB) {
  __shared__ int cnt[SBW];
  __shared__ int sc[SBW];
  __shared__ int cur[SBW];
  const int tid = threadIdx.x;
  if ((int)blockIdx.x < NSB) {
    // ---------------- CSR path ----------------
    const int b = blockIdx.x;
    cnt[tid] = 0;
    __syncthreads();
    const int ec = min(bcur[b], CAPS);
    const int baseC = b * CAPS;
    const int baseP = b * CAPSP;
    for (int e = tid; e < ec; e += 256)
      atomicAdd(&cnt[coarse[baseC + e] >> 17], 1);
    __syncthreads();
    int v = cnt[tid];
    int pc = (v + 3) & ~3;                      // padded count (x4)
    sc[tid] = pc;
    __syncthreads();
    for (int off = 1; off < SBW; off <<= 1) {
      int y = sc[tid];
      if (tid >= off) y += sc[tid - off];
      __syncthreads();
      sc[tid] = y;
      __syncthreads();
    }
    int pex = sc[tid] - pc;                     // exclusive padded prefix
    cur[tid] = pex;
    int gn = b * SBW + tid;
    if (gn < N)
      meta[gn] = make_int2(baseP + pex, pc | (v << 16));
    __syncthreads();
    for (int e = tid; e < ec; e += 256) {
      unsigned p = coarse[baseC + e];
      int dl = (int)(p >> 17);
      int s = (int)(p & 0x1FFFFu);
      int l = atomicAdd(&cur[dl], 1);
      if (l < CAPSP)                            // overflow guard (never taken)
        colidx[baseP + l] = s;
    }
    // sentinel padding (disjoint from scatter range, no sync needed)
    int pe = pex + pc;
    if (pe > CAPSP) pe = CAPSP;
    for (int l = pex + v; l < pe; ++l) colidx[baseP + l] = N;
    return;
  }
  // ---------------- GEMM0 path ----------------
  constexpr int DOUT = 64;
  constexpr int NTT = 4;
  const int gbid = blockIdx.x - NSB;
  if (gbid == 0 && tid < 16)                   // zero sentinel row N of t
    ((unsigned*)t_out)[(size_t)N * 16 + tid] = 0u;
  const int wv = tid >> 6, lane = tid & 63;
  const int q = lane >> 4, m = lane & 15;
  const int row = gbid * 64 + wv * 16 + m;
  const int rowc = row < N ? row : N - 1;
  const float* xp = &x[(size_t)rowc * 64];
  float4 f0 = *(const float4*)&xp[q * 8];
  float4 f1 = *(const float4*)&xp[q * 8 + 4];
  float4 f2 = *(const float4*)&xp[32 + q * 8];
  float4 f3 = *(const float4*)&xp[32 + q * 8 + 4];
  s16x8 a0, a1;
  a0[0] = (short)f2bf(f0.x); a0[1] = (short)f2bf(f0.y);
  a0[2] = (short)f2bf(f0.z); a0[3] = (short)f2bf(f0.w);
  a0[4] = (short)f2bf(f1.x); a0[5] = (short)f2bf(f1.y);
  a0[6] = (short)f2bf(f1.z); a0[7] = (short)f2bf(f1.w);
  a1[0] = (short)f2bf(f2.x); a1[1] = (short)f2bf(f2.y);
  a1[2] = (short)f2bf(f2.z); a1[3] = (short)f2bf(f2.w);
  a1[4] = (short)f2bf(f3.x); a1[5] = (short)f2bf(f3.y);
  a1[6] = (short)f2bf(f3.z); a1[7] = (short)f2bf(f3.w);

  f32x4 acc[2 * NTT];
#pragma unroll
  for (int c = 0; c < 2 * NTT; ++c) acc[c] = (f32x4){0.f, 0.f, 0.f, 0.f};
#pragma unroll
  for (int c = 0; c < 2 * NTT; ++c) {
    s16x8 b0 = *(const s16x8*)&Wf[(c * 2 + 0) * 512 + lane * 8];
    s16x8 b1 = *(const s16x8*)&Wf[(c * 2 + 1) * 512 + lane * 8];
    acc[c] = __builtin_amdgcn_mfma_f32_16x16x32_bf16(a0, b0, acc[c], 0, 0, 0);
    acc[c] = __builtin_amdgcn_mfma_f32_16x16x32_bf16(a1, b1, acc[c], 0, 0, 0);
  }

  const int orow = gbid * 64 + wv * 16 + q * 4;
#pragma unroll
  for (int c = 0; c < NTT; ++c) {
#pragma unroll
    for (int i = 0; i < 4; ++i) {
      int r_ = orow + i;
      if (r_ < N) t_out[(size_t)r_ * DOUT + c * 16 + m] = f2fp8(acc[c][i]);
    }
  }
#pragma unroll
  for (int c = 0; c < NTT; ++c) {
    float bv = bias[c * 16 + m];
#pragma unroll
    for (int i = 0; i < 4; ++i) {
      int r_ = orow + i;
      if (r_ < N) r_out[(size_t)r_ * 64 + c * 16 + m] = f2bf(acc[NTT + c][i] + bv);
    }
  }
}

// ------- mid/final MFMA dual GEMM, bf16 input, LDS-free --------------------
// TFP8: t out fp8 (layer 1) else bf16 (layer 2). RB16: r out bf16 else fp32.

template <int DOUT, bool TFP8, bool RB16>
__global__ __launch_bounds__(256) void gemm_mfma(const unsigned short* __restrict__ Hm,
                                                 const unsigned short* __restrict__ Wf,
                                                 const float* __restrict__ bias,
                                                 void* __restrict__ t_out,
                                                 void* __restrict__ r_out, int N) {
  constexpr int NTT = DOUT / 16;
  constexpr int ROWB = TFP8 ? DOUT : DOUT * 2;   // t row bytes (always 64 here)
  const int tid = threadIdx.x;
  if (blockIdx.x == 0 && tid < ROWB / 4)        // zero sentinel row N of t
    ((unsigned*)((char*)t_out + (size_t)N * ROWB))[tid] = 0u;
  const int wv = tid >> 6, lane = tid & 63;
  const int q = lane >> 4, m = lane & 15;
  const int row = blockIdx.x * 64 + wv * 16 + m;
  const int rowc = row < N ? row : N - 1;
  const s16x8 a0 = *(const s16x8*)&Hm[(size_t)rowc * 64 + q * 8];
  const s16x8 a1 = *(const s16x8*)&Hm[(size_t)rowc * 64 + 32 + q * 8];

  f32x4 acc[2 * NTT];
#pragma unroll
  for (int c = 0; c < 2 * NTT; ++c) acc[c] = (f32x4){0.f, 0.f, 0.f, 0.f};
#pragma unroll
  for (int c = 0; c < 2 * NTT; ++c) {
    s16x8 b0 = *(const s16x8*)&Wf[(c * 2 + 0) * 512 + lane * 8];
    s16x8 b1 = *(const s16x8*)&Wf[(c * 2 + 1) * 512 + lane * 8];
    acc[c] = __builtin_amdgcn_mfma_f32_16x16x32_bf16(a0, b0, acc[c], 0, 0, 0);
    acc[c] = __builtin_amdgcn_mfma_f32_16x16x32_bf16(a1, b1, acc[c], 0, 0, 0);
  }

  const int orow = blockIdx.x * 64 + wv * 16 + q * 4;
#pragma unroll
  for (int c = 0; c < NTT; ++c) {
#pragma unroll
    for (int i = 0; i < 4; ++i) {
      int r_ = orow + i;
      if (r_ < N) {
        if (TFP8)
          ((unsigned char*)t_out)[(size_t)r_ * DOUT + c * 16 + m] = f2fp8(acc[c][i]);
        else
          ((unsigned short*)t_out)[(size_t)r_ * DOUT + c * 16 + m] = f2bf(acc[c][i]);
      }
    }
  }
#pragma unroll
  for (int c = 0; c < NTT; ++c) {
    float bv = bias[c * 16 + m];
#pragma unroll
    for (int i = 0; i < 4; ++i) {
      int r_ = orow + i;
      if (r_ < N) {
        if (RB16)
          ((unsigned short*)r_out)[(size_t)r_ * DOUT + c * 16 + m] =
              f2bf(acc[NTT + c][i] + bv);
        else
          ((float*)r_out)[(size_t)r_ * DOUT + c * 16 + m] = acc[NTT + c][i] + bv;
      }
    }
  }
}

// ------- gather (fp8 t): h = bf16(elu(deg_inv * sum t[src] + r)) -----------
// 4 lanes/node, uint4/lane = 16 fp8 feats (16B load, half the vmem instrs of
// 8x8B); software-pipelined colidx prefetch breaks the colidx->t miss chain;
// per-node meta in one int2. Segments padded to x4; sentinel row N zero.

__global__ __launch_bounds__(256) void gather_fp8(const u32x4* __restrict__ t,
                                                  const unsigned short* __restrict__ r,
                                                  const int2* __restrict__ meta,
                                                  const int* __restrict__ colidx,
                                                  unsigned short* __restrict__ Xout,
                                                  int N) {
  const int node = blockIdx.x * 64 + ((int)threadIdx.x >> 2);
  const int lane = threadIdx.x & 3;
  if (node >= N) return;
  const int2 mt = meta[node];
  const int b = mt.x;
  const int pc = mt.y & 0xFFFF;
  const int vr = mt.y >> 16;
  const int e = b + pc;                        // padded, multiple of 4
  float s[16];
#pragma unroll
  for (int k = 0; k < 16; ++k) s[k] = 0.f;
  int i = b;
  // prefetched colidx (reads may overrun segment by <=32B into valid ws mem)
  i32x4 c0 = __builtin_nontemporal_load((const i32x4*)&colidx[i]);
  i32x4 c1 = __builtin_nontemporal_load((const i32x4*)&colidx[i + 4]);
  for (; i + 8 <= e;) {
    i32x4 p0 = c0, p1 = c1;
    i += 8;
    c0 = __builtin_nontemporal_load((const i32x4*)&colidx[i]);
    c1 = __builtin_nontemporal_load((const i32x4*)&colidx[i + 4]);
    u32x4 v[8];
    v[0] = t[(size_t)p0.x * 4 + lane];
    v[1] = t[(size_t)p0.y * 4 + lane];
    v[2] = t[(size_t)p0.z * 4 + lane];
    v[3] = t[(size_t)p0.w * 4 + lane];
    v[4] = t[(size_t)p1.x * 4 + lane];
    v[5] = t[(size_t)p1.y * 4 + lane];
    v[6] = t[(size_t)p1.z * 4 + lane];
    v[7] = t[(size_t)p1.w * 4 + lane];
#pragma unroll
    for (int j = 0; j < 8; ++j) {
#pragma unroll
      for (int w2 = 0; w2 < 4; ++w2) {
        f32x2 plo = __builtin_amdgcn_cvt_pk_f32_fp8((int)v[j][w2], false);
        f32x2 phi = __builtin_amdgcn_cvt_pk_f32_fp8((int)v[j][w2], true);
        s[w2 * 4 + 0] += plo[0]; s[w2 * 4 + 1] += plo[1];
        s[w2 * 4 + 2] += phi[0]; s[w2 * 4 + 3] += phi[1];
      }
    }
  }
  if (i < e) {                                 // exactly 4 remain (in c0)
    u32x4 v[4];
    v[0] = t[(size_t)c0.x * 4 + lane];
    v[1] = t[(size_t)c0.y * 4 + lane];
    v[2] = t[(size_t)c0.z * 4 + lane];
    v[3] = t[(size_t)c0.w * 4 + lane];
#pragma unroll
    for (int j = 0; j < 4; ++j) {
#pragma unroll
      for (int w2 = 0; w2 < 4; ++w2) {
        f32x2 plo = __builtin_amdgcn_cvt_pk_f32_fp8((int)v[j][w2], false);
        f32x2 phi = __builtin_amdgcn_cvt_pk_f32_fp8((int)v[j][w2], true);
        s[w2 * 4 + 0] += plo[0]; s[w2 * 4 + 1] += plo[1];
        s[w2 * 4 + 2] += phi[0]; s[w2 * 4 + 3] += phi[1];
      }
    }
  }
  const float dv = 1.0f / (float)(vr > 1 ? vr : 1);
  const s16x8 r0 = __builtin_nontemporal_load(
      (const s16x8*)&r[(size_t)node * 64 + lane * 16]);
  const s16x8 r1 = __builtin_nontemporal_load(
      (const s16x8*)&r[(size_t)node * 64 + lane * 16 + 8]);
  s16x8 h0, h1;
#pragma unroll
  for (int k = 0; k < 8; ++k) {
    float ak = s[k] * dv + bf2f((unsigned short)r0[k]);
    ak = ak > 0.f ? ak : (expf(ak) - 1.f);
    h0[k] = (short)f2bf(ak);
    float bk = s[8 + k] * dv + bf2f((unsigned short)r1[k]);
    bk = bk > 0.f ? bk : (expf(bk) - 1.f);
    h1[k] = (short)f2bf(bk);
  }
  __builtin_nontemporal_store(h0, (s16x8*)&Xout[(size_t)node * 64 + lane * 16]);
  __builtin_nontemporal_store(h1, (s16x8*)&Xout[(size_t)node * 64 + lane * 16 + 8]);
}

// ------- final gather: out = deg_inv * sum t2[src] + r[dst], t2 bf16 -------
// 4 lanes/node, uint4/lane = 8 bf16 feats; same prefetch structure.

__global__ __launch_bounds__(256) void gather_out(const u32x4* __restrict__ t,
                                                  const float* __restrict__ r,
                                                  const int2* __restrict__ meta,
                                                  const int* __restrict__ colidx,
                                                  float* __restrict__ out, int N) {
  const int node = blockIdx.x * 64 + ((int)threadIdx.x >> 2);
  const int lane = threadIdx.x & 3;
  if (node >= N) return;
  const int2 mt = meta[node];
  const int b = mt.x;
  const int pc = mt.y & 0xFFFF;
  const int vr = mt.y >> 16;
  const int e = b + pc;                // padded, multiple of 4
  float s[8];
#pragma unroll
  for (int k = 0; k < 8; ++k) s[k] = 0.f;
  int i = b;
  i32x4 c0 = __builtin_nontemporal_load((const i32x4*)&colidx[i]);
  i32x4 c1 = __builtin_nontemporal_load((const i32x4*)&colidx[i + 4]);
  for (; i + 8 <= e;) {
    i32x4 p0 = c0, p1 = c1;
    i += 8;
    c0 = __builtin_nontemporal_load((const i32x4*)&colidx[i]);
    c1 = __builtin_nontemporal_load((const i32x4*)&colidx[i + 4]);
    u32x4 v[8];
    v[0] = t[(size_t)p0.x * 4 + lane];
    v[1] = t[(size_t)p0.y * 4 + lane];
    v[2] = t[(size_t)p0.z * 4 + lane];
    v[3] = t[(size_t)p0.w * 4 + lane];
    v[4] = t[(size_t)p1.x * 4 + lane];
    v[5] = t[(size_t)p1.y * 4 + lane];
    v[6] = t[(size_t)p1.z * 4 + lane];
    v[7] = t[(size_t)p1.w * 4 + lane];
#pragma unroll
    for (int j = 0; j < 8; ++j) {
#pragma unroll
      for (int w2 = 0; w2 < 4; ++w2) {
        s[w2 * 2 + 0] += bf2f((unsigned short)(v[j][w2] & 0xFFFFu));
        s[w2 * 2 + 1] += bf2f((unsigned short)(v[j][w2] >> 16));
      }
    }
  }
  if (i < e) {                          // exactly 4 remain (in c0)
    u32x4 v[4];
    v[0] = t[(size_t)c0.x * 4 + lane];
    v[1] = t[(size_t)c0.y * 4 + lane];
    v[2] = t[(size_t)c0.z * 4 + lane];
    v[3] = t[(size_t)c0.w * 4 + lane];
#pragma unroll
    for (int j = 0; j < 4; ++j) {
#pragma unroll
      for (int w2 = 0; w2 < 4; ++w2) {
        s[w2 * 2 + 0] += bf2f((unsigned short)(v[j][w2] & 0xFFFFu));
        s[w2 * 2 + 1] += bf2f((unsigned short)(v[j][w2] >> 16));
      }
    }
  }
  const float dv = 1.0f / (float)(vr > 1 ? vr : 1);
  f32x4 r0 = __builtin_nontemporal_load((const f32x4*)&r[(size_t)node * 32 + lane * 8]);
  f32x4 r1 = __builtin_nontemporal_load((const f32x4*)&r[(size_t)node * 32 + lane * 8 + 4]);
  f32x4 o0, o1;
#pragma unroll
  for (int k = 0; k < 4; ++k) {
    o0[k] = s[k] * dv + r0[k];
    o1[k] = s[4 + k] * dv + r1[k];
  }
  __builtin_nontemporal_store(o0, (f32x4*)&out[(size_t)node * 32 + lane * 8]);
  __builtin_nontemporal_store(o1, (f32x4*)&out[(size_t)node * 32 + lane * 8 + 4]);
}

// ---------------- launch ----------------

extern "C" void kernel_launch(void* const* d_in, const int* in_sizes, int n_in,
                              void* d_out, int out_size, void* d_ws, size_t ws_size,
                              hipStream_t stream) {
  const float* x   = (const float*)d_in[0];
  const int*   ei  = (const int*)d_in[1];
  const float* Wl0 = (const float*)d_in[2];
  const float* Wr0 = (const float*)d_in[3];
  const float* b0  = (const float*)d_in[4];
  const float* Wl1 = (const float*)d_in[5];
  const float* Wr1 = (const float*)d_in[6];
  const float* b1  = (const float*)d_in[7];
  const float* Wl2 = (const float*)d_in[8];
  const float* Wr2 = (const float*)d_in[9];
  const float* b2  = (const float*)d_in[10];
  float* out = (float*)d_out;

  const int N = in_sizes[0] / 64;   // 100000
  const int E = in_sizes[1] / 2;    // 1600000
  const int* srcv = ei;
  const int* dstv = ei + E;
  const int NSB = (N + SBW - 1) >> LOGSBW;   // 391

  auto al = [](size_t v) { return (v + 255) & ~(size_t)255; };
  char* w = (char*)d_ws;
  size_t oBcur = 0;
  size_t oMeta = oBcur + al(4 * (size_t)NSB);
  size_t oWsw  = oMeta + al(8 * (size_t)N);
  size_t oBin  = oWsw + al(2 * 20480);
  size_t oCol  = oBin + al(4 * (size_t)NSB * CAPS);
  size_t oP8   = oCol + al(4 * (size_t)NSB * CAPSP);
  size_t oP16  = oP8 + al((size_t)(N + 1) * 64);   // fp8 t0/t1 (+sentinel row)
  size_t oX    = oP16 + al((size_t)(N + 1) * 64);  // bf16 t2 (+sentinel row)
  size_t oR    = oX + al(2 * (size_t)N * 64);      // bf16 h buffer
  // total = oR + 2*N*64  (~55 MiB); r buffer: bf16 [N][64] or fp32 [N][32]

  int*            bcur     = (int*)(w + oBcur);
  int2*           meta     = (int2*)(w + oMeta);
  unsigned short* Wsw      = (unsigned short*)(w + oWsw); // swizzled weights
  unsigned*       coarse   = (unsigned*)(w + oBin);
  int*            colidx   = (int*)(w + oCol);
  unsigned char*  P8       = (unsigned char*)(w + oP8);   // fp8 t0/t1
  unsigned short* P16      = (unsigned short*)(w + oP16); // bf16 t2
  unsigned short* X        = (unsigned short*)(w + oX);   // bf16 h
  unsigned short* Rb       = (unsigned short*)(w + oR);   // bf16 r (L0/L1)
  float*          Rf       = (float*)(w + oR);            // fp32 r (L2)

  int bbl = (E + CHK - 1) / CHK;   // 782
  int gb = (N + 63) / 64;          // 1563
  int ggb = (N + 63) / 64;         // 1563 (64 nodes/block, 4 lanes/node)

  init_ws<<<41, 256, 0, stream>>>(bcur, NSB, Wl0, Wr0, Wl1, Wr1, Wl2, Wr2, Wsw);
  bin_coarse<<<bbl, 256, 0, stream>>>(srcv, dstv, bcur, coarse, NSB, E);
  // CSR build (blocks [0,NSB)) overlapped with layer-0 GEMM (blocks [NSB,..))
  csr_gemm0<<<NSB + gb, 256, 0, stream>>>(coarse, bcur, meta, colidx, x, Wsw,
                                          b0, P8, Rb, N, NSB);
  gather_fp8<<<ggb, 256, 0, stream>>>((const u32x4*)P8, Rb, meta, colidx, X, N);
  // layer 1: X -> t1 (fp8 P8), r1 (bf16 Rb)
  gemm_mfma<64, true, true><<<gb, 256, 0, stream>>>(X, Wsw + 8192, b1, P8, Rb, N);
  gather_fp8<<<ggb, 256, 0, stream>>>((const u32x4*)P8, Rb, meta, colidx, X, N);
  // layer 2: X -> t2 (bf16 P16), r2 (fp32 Rf, [N][32])
  gemm_mfma<32, false, false><<<gb, 256, 0, stream>>>(X, Wsw + 16384, b2, P16, Rf, N);
  gather_out<<<ggb, 256, 0, stream>>>((const u32x4*)P16, Rf, meta, colidx, out, N);
}